// Round 1
// baseline (89.431 us; speedup 1.0000x reference)
//
#include <hip/hip_runtime.h>
#include <math.h>

#define N 8192
#define D 3072

// Kernel 1: one block per row. Computes s[i] = sum_d x[i,d] and
// pred[i] = dot(x[i,:], w[0:D]) + w[D] in a single pass over x.
__global__ __launch_bounds__(256) void rowsum_dot_kernel(
    const float* __restrict__ x, const float* __restrict__ w,
    float* __restrict__ s, float* __restrict__ pred) {
    const int i = blockIdx.x;
    const int tid = threadIdx.x;
    const float* xrow = x + (size_t)i * D;

    float sum = 0.f, dot = 0.f;
    // 3072 floats / 256 threads = 12 each = 3 float4, coalesced
    #pragma unroll
    for (int k = 0; k < 3; ++k) {
        const int idx = (tid + k * 256) * 4;
        const float4 xv = *reinterpret_cast<const float4*>(xrow + idx);
        const float4 wv = *reinterpret_cast<const float4*>(w + idx);
        sum += (xv.x + xv.y) + (xv.z + xv.w);
        dot += xv.x * wv.x + xv.y * wv.y + xv.z * wv.z + xv.w * wv.w;
    }
    // wave(64) butterfly reduce both values
    #pragma unroll
    for (int off = 32; off > 0; off >>= 1) {
        sum += __shfl_down(sum, off, 64);
        dot += __shfl_down(dot, off, 64);
    }
    __shared__ float lsum[4], ldot[4];
    const int wave = tid >> 6;
    if ((tid & 63) == 0) { lsum[wave] = sum; ldot[wave] = dot; }
    __syncthreads();
    if (tid == 0) {
        const float S  = (lsum[0] + lsum[1]) + (lsum[2] + lsum[3]);
        const float Dt = (ldot[0] + ldot[1]) + (ldot[2] + ldot[3]);
        s[i] = S;
        pred[i] = Dt + w[D];  // bias column of ones
    }
}

// Kernel 2: one block per row of K. K[i,j] = exp(s[j] - s[i]).
// K base is at float offset 8193 in d_out => each row base is ≡1 (mod 4
// floats). Peel 3-head + 1-tail scalars so the bulk is aligned float4.
__global__ __launch_bounds__(256) void kmat_kernel(
    const float* __restrict__ s, float* __restrict__ K) {
    const int i = blockIdx.x;
    const int tid = threadIdx.x;
    const float si = s[i];
    float* __restrict__ row = K + (size_t)i * N;

    if (tid < 3) row[tid] = __expf(s[tid] - si);
    if (tid == 3) row[N - 1] = __expf(s[N - 1] - si);

    // vector body: j = 3 .. 8190, 2047 float4 chunks
    for (int v = tid; v < 2047; v += 256) {
        const int j = 3 + v * 4;
        float4 o;
        o.x = __expf(s[j + 0] - si);
        o.y = __expf(s[j + 1] - si);
        o.z = __expf(s[j + 2] - si);
        o.w = __expf(s[j + 3] - si);
        *reinterpret_cast<float4*>(row + j) = o;  // 16B-aligned (8193+3 ≡ 0 mod 4)
    }
}

// Kernel 3: single-block loss reduction.
// loss = 0.5*sqrt(sum((y - pred)^2))/N + sum(|w|)
__global__ __launch_bounds__(1024) void loss_kernel(
    const float* __restrict__ pred, const int* __restrict__ y,
    const float* __restrict__ w, float* __restrict__ loss_out) {
    const int tid = threadIdx.x;
    float acc = 0.f;
    for (int i = tid; i < N; i += 1024) {
        const float d = (float)y[i] - pred[i];
        acc += d * d;
    }
    float wacc = 0.f;
    for (int i = tid; i < D + 1; i += 1024) wacc += fabsf(w[i]);

    #pragma unroll
    for (int off = 32; off > 0; off >>= 1) {
        acc  += __shfl_down(acc, off, 64);
        wacc += __shfl_down(wacc, off, 64);
    }
    __shared__ float la[16], lw[16];
    const int wave = tid >> 6;
    if ((tid & 63) == 0) { la[wave] = acc; lw[wave] = wacc; }
    __syncthreads();
    if (tid == 0) {
        float a = 0.f, b = 0.f;
        #pragma unroll
        for (int k = 0; k < 16; ++k) { a += la[k]; b += lw[k]; }
        loss_out[0] = 0.5f * sqrtf(a) / (float)N + b;
    }
}

extern "C" void kernel_launch(void* const* d_in, const int* in_sizes, int n_in,
                              void* d_out, int out_size, void* d_ws, size_t ws_size,
                              hipStream_t stream) {
    const float* x = (const float*)d_in[0];   // [8192, 3072] f32
    const int*   y = (const int*)d_in[1];     // [8192, 1] i32
    const float* w = (const float*)d_in[2];   // [3073, 1] f32

    float* out  = (float*)d_out;
    float* pred = out;              // [8192]
    float* loss = out + N;          // [1]
    float* K    = out + N + 1;      // [8192, 8192]
    float* s    = (float*)d_ws;     // [8192] row sums

    rowsum_dot_kernel<<<N, 256, 0, stream>>>(x, w, s, pred);
    kmat_kernel<<<N, 256, 0, stream>>>(s, K);
    loss_kernel<<<1, 1024, 0, stream>>>(pred, y, w, loss);
}